// Round 2
// baseline (2202.776 us; speedup 1.0000x reference)
//
#include <hip/hip_runtime.h>
#include <cstdint>
#include <cstddef>

#define B_ROWS 16384
#define EMB_LEN 16384
#define K_DIM 128
#define JSPLIT 8
#define JLEN (EMB_LEN / JSPLIT)   // 2048
#define RB 64                     // rows per block
#define JT 256                    // j-tile
#define KC 16                     // k chunk
#define NSTAGE ((JLEN / JT) * (K_DIM / KC))   // 8*8 = 64

// ---------------------------------------------------------------------------
// Kernel 1: zf + C per row.  (UNCHANGED from round 1 — passed with absmax 0;
// Cb's fp32 summation order is part of the frozen arithmetic contract.)
// ---------------------------------------------------------------------------
__global__ void zf_kernel(const float* __restrict__ z,
                          float* __restrict__ zf, float* __restrict__ Cb) {
    int b = blockIdx.x;
    int i = threadIdx.x;                 // 0..127
    int c = i >> 3, h = (i >> 1) & 1, wp = i & 1;
    const float* zr = z + (size_t)b * 128 + c * 8 + h * 4 + wp * 2;
    float v = 0.5f * zr[0] + 0.5f * zr[1];
    zf[(size_t)b * 128 + i] = v;
    float s = v * v;
    for (int o = 32; o; o >>= 1) s += __shfl_down(s, o, 64);
    __shared__ float sm[2];
    if ((threadIdx.x & 63) == 0) sm[threadIdx.x >> 6] = s;
    __syncthreads();
    if (threadIdx.x == 0) Cb[b] = sm[0] + sm[1];
}

// ---------------------------------------------------------------------------
// Kernel 2: argmin of d = C - 2*dot(zf, e_j), restructured.
// wave w owns rows [w*8, w*8+8) (a-read: 2x b128 wave-uniform broadcast);
// lane l owns j = jt + l*4 .. +3 (b-read: 1x b128, lanes contiguous -> 0-conflict).
// 32 FMA per 3 LDS reads. es chunk prefetched into regs during compute.
// Arithmetic contract: per (r,j) single fp32 FMA chain ascending k; d = C-2g;
// strict < argmin (earliest j wins). DO NOT change.
// ---------------------------------------------------------------------------
__launch_bounds__(512, 4)
__global__ void argmin_kernel(const float* __restrict__ zf,
                              const float* __restrict__ Cb,
                              const float* __restrict__ emb,
                              float* __restrict__ cand_d,
                              int* __restrict__ cand_j) {
    __shared__ float zfs[K_DIM][RB + 4];   // [k][r], +4 pad for transpose writes (~34 KB)
    __shared__ float es[KC][JT];           // [k][j] staged chunk (16 KB)

    int rb = blockIdx.x & 255;
    int sp = blockIdx.x >> 8;          // 0..7
    int rbase = rb * RB;
    int jbase = sp * JLEN;
    int tid = threadIdx.x;
    int w = tid >> 6;                  // wave 0..7
    int l = tid & 63;
    int w8 = w << 3;
    int l4 = l << 2;

    // stage zfs transposed: zfs[k][r]
    {
        int r0 = tid >> 3;             // 0..63
        int kq0 = tid & 7;             // 0..7
        const float* zr = zf + (size_t)(rbase + r0) * 128;
        for (int kq = kq0; kq < 32; kq += 8) {
            float4 v = *(const float4*)(zr + kq * 4);
            zfs[kq * 4 + 0][r0] = v.x;
            zfs[kq * 4 + 1][r0] = v.y;
            zfs[kq * 4 + 2][r0] = v.z;
            zfs[kq * 4 + 3][r0] = v.w;
        }
    }

    // wave-uniform row constants
    float cb[8];
#pragma unroll
    for (int r = 0; r < 8; ++r) cb[r] = Cb[rbase + w8 + r];

    float bestd[8];
    int bestj[8];
#pragma unroll
    for (int r = 0; r < 8; ++r) { bestd[r] = 3.4e38f; bestj[r] = 0; }

    // es staging mapping: thread loads 2 float4 per chunk.
    // j0 = tid>>2 (0..127), kq = tid&3; second load at j0+128.
    // Global: 4 lanes cover one 64-B line of a j-row (no over-fetch).
    int sj0 = tid >> 2;
    int skq = tid & 3;

    // prefetch stage 0 (jt=0, kc=0)
    const float* eb0 = emb + (size_t)(jbase + sj0) * 128 + skq * 4;
    float4 pre0 = *(const float4*)(eb0);
    float4 pre1 = *(const float4*)(eb0 + (size_t)128 * 128);

    float acc[8][4];

    for (int s = 0; s < NSTAGE; ++s) {
        int jt = (s >> 3) * JT;
        int kc = (s & 7) * KC;

        __syncthreads();   // prior chunk's es reads done (covers zfs staging at s=0)
        {
            es[skq * 4 + 0][sj0] = pre0.x;
            es[skq * 4 + 1][sj0] = pre0.y;
            es[skq * 4 + 2][sj0] = pre0.z;
            es[skq * 4 + 3][sj0] = pre0.w;
            es[skq * 4 + 0][sj0 + 128] = pre1.x;
            es[skq * 4 + 1][sj0 + 128] = pre1.y;
            es[skq * 4 + 2][sj0 + 128] = pre1.z;
            es[skq * 4 + 3][sj0 + 128] = pre1.w;
        }
        __syncthreads();   // es ready

        // prefetch next chunk (in flight during compute)
        if (s + 1 < NSTAGE) {
            int jt2 = ((s + 1) >> 3) * JT;
            int kc2 = ((s + 1) & 7) * KC;
            const float* eb = emb + (size_t)(jbase + jt2 + sj0) * 128 + kc2 + skq * 4;
            pre0 = *(const float4*)(eb);
            pre1 = *(const float4*)(eb + (size_t)128 * 128);
        }

        if ((s & 7) == 0) {
#pragma unroll
            for (int r = 0; r < 8; ++r)
#pragma unroll
                for (int j = 0; j < 4; ++j) acc[r][j] = 0.0f;
        }

#pragma unroll
        for (int k = 0; k < KC; ++k) {
            const float4 a0 = *(const float4*)(&zfs[kc + k][w8]);
            const float4 a1 = *(const float4*)(&zfs[kc + k][w8 + 4]);
            const float4 bv = *(const float4*)(&es[k][l4]);
            float a[8] = {a0.x, a0.y, a0.z, a0.w, a1.x, a1.y, a1.z, a1.w};
            float b[4] = {bv.x, bv.y, bv.z, bv.w};
#pragma unroll
            for (int r = 0; r < 8; ++r)
#pragma unroll
                for (int j = 0; j < 4; ++j)
                    acc[r][j] = fmaf(a[r], b[j], acc[r][j]);
        }

        if ((s & 7) == 7) {
            // epilogue for this jt: d = C - 2g; strict < keeps earliest j
#pragma unroll
            for (int ji = 0; ji < 4; ++ji) {
                int j = jbase + jt + l4 + ji;
#pragma unroll
                for (int r = 0; r < 8; ++r) {
                    float dv = cb[r] - 2.0f * acc[r][ji];
                    if (dv < bestd[r]) { bestd[r] = dv; bestj[r] = j; }
                }
            }
        }
    }

    // cross-lane lexicographic (d, j) min per row (rows are wave-exclusive)
#pragma unroll
    for (int r = 0; r < 8; ++r) {
        float bd = bestd[r];
        int bj = bestj[r];
        for (int o = 32; o; o >>= 1) {
            float d2 = __shfl_down(bd, o, 64);
            int j2 = __shfl_down(bj, o, 64);
            if (d2 < bd || (d2 == bd && j2 < bj)) { bd = d2; bj = j2; }
        }
        if (l == 0) {
            cand_d[sp * B_ROWS + rbase + w8 + r] = bd;
            cand_j[sp * B_ROWS + rbase + w8 + r] = bj;
        }
    }
}

// ---------------------------------------------------------------------------
// Kernel 3: merge splits (ascending split + strict < => smallest j wins ties)
// ---------------------------------------------------------------------------
__global__ void merge_kernel(const float* __restrict__ cand_d,
                             const int* __restrict__ cand_j,
                             int* __restrict__ idxw,
                             float* __restrict__ out_idx) {
    int b = blockIdx.x * 256 + threadIdx.x;
    float bd = cand_d[b];
    int bj = cand_j[b];
#pragma unroll
    for (int s = 1; s < JSPLIT; ++s) {
        float d = cand_d[s * B_ROWS + b];
        int j = cand_j[s * B_ROWS + b];
        if (d < bd) { bd = d; bj = j; }
    }
    idxw[b] = bj;
    out_idx[b] = (float)bj;
}

// ---------------------------------------------------------------------------
// Kernel 4: z_q_out (transposed) + moment sums for loss
// ---------------------------------------------------------------------------
__global__ void output_kernel(const float* __restrict__ z,
                              const float* __restrict__ emb,
                              const int* __restrict__ idxw,
                              float* __restrict__ out,
                              double* __restrict__ accs) {
    int stride = gridDim.x * blockDim.x;
    double s[6] = {0, 0, 0, 0, 0, 0};
    for (int n = blockIdx.x * blockDim.x + threadIdx.x; n < B_ROWS * 128; n += stride) {
        int b = n >> 7, i = n & 127;
        int c = i >> 3, h = (i >> 2) & 1, w = i & 3;   // i = c*8 + h*4 + w
        float zv = z[n];
        float qv = emb[(size_t)idxw[b] * 128 + i];
        float diff = qv - zv;                          // z_q - z (fp32, as ref)
        out[(size_t)((b * 4 + w) * 16 + c) * 2 + h] = zv + diff;
        s[0] += (double)qv;
        s[1] += (double)zv;
        s[2] += (double)qv * qv;
        s[3] += (double)zv * zv;
        s[4] += (double)qv * zv;
        s[5] += (double)diff * diff;
    }
    int lane = threadIdx.x & 63, wv = threadIdx.x >> 6;
#pragma unroll
    for (int q = 0; q < 6; ++q)
        for (int o = 32; o; o >>= 1) s[q] += __shfl_down(s[q], o, 64);
    __shared__ double sm[6][4];
    if (lane == 0)
#pragma unroll
        for (int q = 0; q < 6; ++q) sm[q][wv] = s[q];
    __syncthreads();
    if (threadIdx.x == 0) {
#pragma unroll
        for (int q = 0; q < 6; ++q)
            atomicAdd(&accs[q], sm[q][0] + sm[q][1] + sm[q][2] + sm[q][3]);
    }
}

// ---------------------------------------------------------------------------
// Kernel 5: per-column L1 of emb (for reg term)
// ---------------------------------------------------------------------------
__global__ void colsum_kernel(const float* __restrict__ emb, float* __restrict__ colsum) {
    int j = blockIdx.x;   // 0..127
    double s = 0;
    for (int i = threadIdx.x; i < EMB_LEN; i += blockDim.x)
        s += (double)fabsf(emb[(size_t)i * 128 + j]);
    int lane = threadIdx.x & 63, wv = threadIdx.x >> 6;
    for (int o = 32; o; o >>= 1) s += __shfl_down(s, o, 64);
    __shared__ double sm[4];
    if (lane == 0) sm[wv] = s;
    __syncthreads();
    if (threadIdx.x == 0) colsum[j] = (float)(sm[0] + sm[1] + sm[2] + sm[3]);
}

// ---------------------------------------------------------------------------
// Kernel 6: final loss
// ---------------------------------------------------------------------------
__global__ void loss_kernel(const double* __restrict__ accs,
                            const float* __restrict__ colsum,
                            float* __restrict__ out_loss) {
    __shared__ float sm[128];
    int tid = threadIdx.x;
    sm[tid] = colsum[tid];
    __syncthreads();
    for (int s = 64; s; s >>= 1) {
        if (tid < s) sm[tid] = fmaxf(sm[tid], sm[tid + s]);
        __syncthreads();
    }
    if (tid == 0) {
        double n = (double)B_ROWS * 128.0;
        double m = accs[5] / n;                   // mean((z_q - z)^2)
        double commit = 0.25 * m + m;
        double Sx = accs[0], Sy = accs[1], Sxx = accs[2], Syy = accs[3], Sxy = accs[4];
        double cov = Sxy - Sx * Sy / n;
        double vx = Sxx - Sx * Sx / n;
        double vy = Syy - Sy * Sy / n;
        double pearson = 0.5 + 0.5 * cov / (sqrt(vx) * sqrt(vy));
        double reg = 0.01 * (double)sm[0];
        out_loss[0] = (float)(commit + pearson + reg);
    }
}

// ---------------------------------------------------------------------------
extern "C" void kernel_launch(void* const* d_in, const int* in_sizes, int n_in,
                              void* d_out, int out_size, void* d_ws, size_t ws_size,
                              hipStream_t stream) {
    const float* z = (const float*)d_in[0];      // 16384*16*2*4
    const float* emb = (const float*)d_in[1];    // 16384*128
    float* out = (float*)d_out;                  // 2097152 (z_q_out) + 1 (loss) + 16384 (idx)

    float* zf = (float*)d_ws;                    // 2097152 floats
    float* Cb = zf + 2097152;                    // 16384
    float* cand_d = Cb + 16384;                  // JSPLIT*16384
    int* cand_j = (int*)(cand_d + JSPLIT * B_ROWS);
    int* idxw = cand_j + JSPLIT * B_ROWS;        // 16384
    double* accs = (double*)(idxw + 16384);      // 8 doubles
    float* colsum = (float*)(accs + 8);          // 128

    hipMemsetAsync(accs, 0, 8 * sizeof(double), stream);

    zf_kernel<<<B_ROWS, 128, 0, stream>>>(z, zf, Cb);
    argmin_kernel<<<256 * JSPLIT, 512, 0, stream>>>(zf, Cb, emb, cand_d, cand_j);
    merge_kernel<<<B_ROWS / 256, 256, 0, stream>>>(cand_d, cand_j, idxw, out + 2097153);
    output_kernel<<<1024, 256, 0, stream>>>(z, emb, idxw, out, accs);
    colsum_kernel<<<128, 256, 0, stream>>>(emb, colsum);
    loss_kernel<<<1, 128, 0, stream>>>(accs, colsum, out + 2097152);
}

// Round 3
// 2131.753 us; speedup vs baseline: 1.0333x; 1.0333x over previous
//
#include <hip/hip_runtime.h>
#include <cstdint>
#include <cstddef>

#define B_ROWS 16384
#define EMB_LEN 16384
#define K_DIM 128
#define JSPLIT 8
#define JLEN (EMB_LEN / JSPLIT)   // 2048
#define RB 64                     // rows per block
#define JT 256                    // j-tile
#define KC 16                     // k chunk
#define NSTAGE ((JLEN / JT) * (K_DIM / KC))   // 8*8 = 64

// ---------------------------------------------------------------------------
// Kernel 1: zf + C per row.  (frozen — absmax 0 in R1/R2)
// ---------------------------------------------------------------------------
__global__ void zf_kernel(const float* __restrict__ z,
                          float* __restrict__ zf, float* __restrict__ Cb) {
    int b = blockIdx.x;
    int i = threadIdx.x;                 // 0..127
    int c = i >> 3, h = (i >> 1) & 1, wp = i & 1;
    const float* zr = z + (size_t)b * 128 + c * 8 + h * 4 + wp * 2;
    float v = 0.5f * zr[0] + 0.5f * zr[1];
    zf[(size_t)b * 128 + i] = v;
    float s = v * v;
    for (int o = 32; o; o >>= 1) s += __shfl_down(s, o, 64);
    __shared__ float sm[2];
    if ((threadIdx.x & 63) == 0) sm[threadIdx.x >> 6] = s;
    __syncthreads();
    if (threadIdx.x == 0) Cb[b] = sm[0] + sm[1];
}

// ---------------------------------------------------------------------------
// Kernel 2: argmin of d = C - 2*dot(zf, e_j).
// R2 structure; R3 changes ONLY occupancy control:
//   - __launch_bounds__(512) + amdgpu_waves_per_eu(4)  (<=128 VGPR budget;
//     R2's (512,4) was read as an 8-wave/EU cap -> 64 VGPRs -> 6.5 GB of
//     accumulator spill traffic -> memory-bound at 2.25 ms)
//   - cb[] moved to LDS (epilogue-only wave-uniform broadcast) to save 8 VGPRs.
// Arithmetic contract (frozen, absmax 0): per (r,j) single fp32 FMA chain
// ascending k; d = C - 2g; strict < argmin; splits merged ascending.
// ---------------------------------------------------------------------------
__global__ void __launch_bounds__(512)
__attribute__((amdgpu_waves_per_eu(4)))
argmin_kernel(const float* __restrict__ zf,
              const float* __restrict__ Cb,
              const float* __restrict__ emb,
              float* __restrict__ cand_d,
              int* __restrict__ cand_j) {
    __shared__ float zfs[K_DIM][RB + 4];   // [k][r], +4 pad (~34 KB)
    __shared__ float es[KC][JT];           // [k][j] staged chunk (16 KB)
    __shared__ float cbs[RB];              // row constants C[b]

    int rb = blockIdx.x & 255;
    int sp = blockIdx.x >> 8;          // 0..7
    int rbase = rb * RB;
    int jbase = sp * JLEN;
    int tid = threadIdx.x;
    int w = tid >> 6;                  // wave 0..7
    int l = tid & 63;
    int w8 = w << 3;
    int l4 = l << 2;

    // stage zfs transposed: zfs[k][r]; stage cbs
    {
        int r0 = tid >> 3;             // 0..63
        int kq0 = tid & 7;             // 0..7
        const float* zr = zf + (size_t)(rbase + r0) * 128;
        for (int kq = kq0; kq < 32; kq += 8) {
            float4 v = *(const float4*)(zr + kq * 4);
            zfs[kq * 4 + 0][r0] = v.x;
            zfs[kq * 4 + 1][r0] = v.y;
            zfs[kq * 4 + 2][r0] = v.z;
            zfs[kq * 4 + 3][r0] = v.w;
        }
        if (tid < RB) cbs[tid] = Cb[rbase + tid];
    }

    float bestd[8];
    int bestj[8];
#pragma unroll
    for (int r = 0; r < 8; ++r) { bestd[r] = 3.4e38f; bestj[r] = 0; }

    // es staging mapping: thread loads 2 float4 per chunk.
    int sj0 = tid >> 2;
    int skq = tid & 3;

    // prefetch stage 0 (jt=0, kc=0)
    const float* eb0 = emb + (size_t)(jbase + sj0) * 128 + skq * 4;
    float4 pre0 = *(const float4*)(eb0);
    float4 pre1 = *(const float4*)(eb0 + (size_t)128 * 128);

    float acc[8][4];

    for (int s = 0; s < NSTAGE; ++s) {
        int jt = (s >> 3) * JT;
        int kc = (s & 7) * KC;

        __syncthreads();   // prior chunk's es reads done (covers zfs/cbs at s=0)
        {
            es[skq * 4 + 0][sj0] = pre0.x;
            es[skq * 4 + 1][sj0] = pre0.y;
            es[skq * 4 + 2][sj0] = pre0.z;
            es[skq * 4 + 3][sj0] = pre0.w;
            es[skq * 4 + 0][sj0 + 128] = pre1.x;
            es[skq * 4 + 1][sj0 + 128] = pre1.y;
            es[skq * 4 + 2][sj0 + 128] = pre1.z;
            es[skq * 4 + 3][sj0 + 128] = pre1.w;
        }
        __syncthreads();   // es ready

        // prefetch next chunk (in flight during compute)
        if (s + 1 < NSTAGE) {
            int jt2 = ((s + 1) >> 3) * JT;
            int kc2 = ((s + 1) & 7) * KC;
            const float* eb = emb + (size_t)(jbase + jt2 + sj0) * 128 + kc2 + skq * 4;
            pre0 = *(const float4*)(eb);
            pre1 = *(const float4*)(eb + (size_t)128 * 128);
        }

        if ((s & 7) == 0) {
#pragma unroll
            for (int r = 0; r < 8; ++r)
#pragma unroll
                for (int j = 0; j < 4; ++j) acc[r][j] = 0.0f;
        }

#pragma unroll
        for (int k = 0; k < KC; ++k) {
            const float4 a0 = *(const float4*)(&zfs[kc + k][w8]);
            const float4 a1 = *(const float4*)(&zfs[kc + k][w8 + 4]);
            const float4 bv = *(const float4*)(&es[k][l4]);
            float a[8] = {a0.x, a0.y, a0.z, a0.w, a1.x, a1.y, a1.z, a1.w};
            float b[4] = {bv.x, bv.y, bv.z, bv.w};
#pragma unroll
            for (int r = 0; r < 8; ++r)
#pragma unroll
                for (int j = 0; j < 4; ++j)
                    acc[r][j] = fmaf(a[r], b[j], acc[r][j]);
        }

        if ((s & 7) == 7) {
            // epilogue for this jt: d = C - 2g; strict < keeps earliest j
#pragma unroll
            for (int ji = 0; ji < 4; ++ji) {
                int j = jbase + jt + l4 + ji;
#pragma unroll
                for (int r = 0; r < 8; ++r) {
                    float dv = cbs[w8 + r] - 2.0f * acc[r][ji];
                    if (dv < bestd[r]) { bestd[r] = dv; bestj[r] = j; }
                }
            }
        }
    }

    // cross-lane lexicographic (d, j) min per row (rows are wave-exclusive)
#pragma unroll
    for (int r = 0; r < 8; ++r) {
        float bd = bestd[r];
        int bj = bestj[r];
        for (int o = 32; o; o >>= 1) {
            float d2 = __shfl_down(bd, o, 64);
            int j2 = __shfl_down(bj, o, 64);
            if (d2 < bd || (d2 == bd && j2 < bj)) { bd = d2; bj = j2; }
        }
        if (l == 0) {
            cand_d[sp * B_ROWS + rbase + w8 + r] = bd;
            cand_j[sp * B_ROWS + rbase + w8 + r] = bj;
        }
    }
}

// ---------------------------------------------------------------------------
// Kernel 3: merge splits (ascending split + strict < => smallest j wins ties)
// ---------------------------------------------------------------------------
__global__ void merge_kernel(const float* __restrict__ cand_d,
                             const int* __restrict__ cand_j,
                             int* __restrict__ idxw,
                             float* __restrict__ out_idx) {
    int b = blockIdx.x * 256 + threadIdx.x;
    float bd = cand_d[b];
    int bj = cand_j[b];
#pragma unroll
    for (int s = 1; s < JSPLIT; ++s) {
        float d = cand_d[s * B_ROWS + b];
        int j = cand_j[s * B_ROWS + b];
        if (d < bd) { bd = d; bj = j; }
    }
    idxw[b] = bj;
    out_idx[b] = (float)bj;
}

// ---------------------------------------------------------------------------
// Kernel 4: z_q_out (transposed) + moment sums for loss
// ---------------------------------------------------------------------------
__global__ void output_kernel(const float* __restrict__ z,
                              const float* __restrict__ emb,
                              const int* __restrict__ idxw,
                              float* __restrict__ out,
                              double* __restrict__ accs) {
    int stride = gridDim.x * blockDim.x;
    double s[6] = {0, 0, 0, 0, 0, 0};
    for (int n = blockIdx.x * blockDim.x + threadIdx.x; n < B_ROWS * 128; n += stride) {
        int b = n >> 7, i = n & 127;
        int c = i >> 3, h = (i >> 2) & 1, w = i & 3;   // i = c*8 + h*4 + w
        float zv = z[n];
        float qv = emb[(size_t)idxw[b] * 128 + i];
        float diff = qv - zv;                          // z_q - z (fp32, as ref)
        out[(size_t)((b * 4 + w) * 16 + c) * 2 + h] = zv + diff;
        s[0] += (double)qv;
        s[1] += (double)zv;
        s[2] += (double)qv * qv;
        s[3] += (double)zv * zv;
        s[4] += (double)qv * zv;
        s[5] += (double)diff * diff;
    }
    int lane = threadIdx.x & 63, wv = threadIdx.x >> 6;
#pragma unroll
    for (int q = 0; q < 6; ++q)
        for (int o = 32; o; o >>= 1) s[q] += __shfl_down(s[q], o, 64);
    __shared__ double sm[6][4];
    if (lane == 0)
#pragma unroll
        for (int q = 0; q < 6; ++q) sm[q][wv] = s[q];
    __syncthreads();
    if (threadIdx.x == 0) {
#pragma unroll
        for (int q = 0; q < 6; ++q)
            atomicAdd(&accs[q], sm[q][0] + sm[q][1] + sm[q][2] + sm[q][3]);
    }
}

// ---------------------------------------------------------------------------
// Kernel 5: per-column L1 of emb (for reg term)
// ---------------------------------------------------------------------------
__global__ void colsum_kernel(const float* __restrict__ emb, float* __restrict__ colsum) {
    int j = blockIdx.x;   // 0..127
    double s = 0;
    for (int i = threadIdx.x; i < EMB_LEN; i += blockDim.x)
        s += (double)fabsf(emb[(size_t)i * 128 + j]);
    int lane = threadIdx.x & 63, wv = threadIdx.x >> 6;
    for (int o = 32; o; o >>= 1) s += __shfl_down(s, o, 64);
    __shared__ double sm[4];
    if (lane == 0) sm[wv] = s;
    __syncthreads();
    if (threadIdx.x == 0) colsum[j] = (float)(sm[0] + sm[1] + sm[2] + sm[3]);
}

// ---------------------------------------------------------------------------
// Kernel 6: final loss
// ---------------------------------------------------------------------------
__global__ void loss_kernel(const double* __restrict__ accs,
                            const float* __restrict__ colsum,
                            float* __restrict__ out_loss) {
    __shared__ float sm[128];
    int tid = threadIdx.x;
    sm[tid] = colsum[tid];
    __syncthreads();
    for (int s = 64; s; s >>= 1) {
        if (tid < s) sm[tid] = fmaxf(sm[tid], sm[tid + s]);
        __syncthreads();
    }
    if (tid == 0) {
        double n = (double)B_ROWS * 128.0;
        double m = accs[5] / n;                   // mean((z_q - z)^2)
        double commit = 0.25 * m + m;
        double Sx = accs[0], Sy = accs[1], Sxx = accs[2], Syy = accs[3], Sxy = accs[4];
        double cov = Sxy - Sx * Sy / n;
        double vx = Sxx - Sx * Sx / n;
        double vy = Syy - Sy * Sy / n;
        double pearson = 0.5 + 0.5 * cov / (sqrt(vx) * sqrt(vy));
        double reg = 0.01 * (double)sm[0];
        out_loss[0] = (float)(commit + pearson + reg);
    }
}

// ---------------------------------------------------------------------------
extern "C" void kernel_launch(void* const* d_in, const int* in_sizes, int n_in,
                              void* d_out, int out_size, void* d_ws, size_t ws_size,
                              hipStream_t stream) {
    const float* z = (const float*)d_in[0];      // 16384*16*2*4
    const float* emb = (const float*)d_in[1];    // 16384*128
    float* out = (float*)d_out;                  // 2097152 (z_q_out) + 1 (loss) + 16384 (idx)

    float* zf = (float*)d_ws;                    // 2097152 floats
    float* Cb = zf + 2097152;                    // 16384
    float* cand_d = Cb + 16384;                  // JSPLIT*16384
    int* cand_j = (int*)(cand_d + JSPLIT * B_ROWS);
    int* idxw = cand_j + JSPLIT * B_ROWS;        // 16384
    double* accs = (double*)(idxw + 16384);      // 8 doubles
    float* colsum = (float*)(accs + 8);          // 128

    hipMemsetAsync(accs, 0, 8 * sizeof(double), stream);

    zf_kernel<<<B_ROWS, 128, 0, stream>>>(z, zf, Cb);
    argmin_kernel<<<256 * JSPLIT, 512, 0, stream>>>(zf, Cb, emb, cand_d, cand_j);
    merge_kernel<<<B_ROWS / 256, 256, 0, stream>>>(cand_d, cand_j, idxw, out + 2097153);
    output_kernel<<<1024, 256, 0, stream>>>(z, emb, idxw, out, accs);
    colsum_kernel<<<128, 256, 0, stream>>>(emb, colsum);
    loss_kernel<<<1, 128, 0, stream>>>(accs, colsum, out + 2097152);
}